// Round 5
// baseline (586.000 us; speedup 1.0000x reference)
//
#include <hip/hip_runtime.h>
#include <hip/hip_bf16.h>

typedef __bf16 bf16;
typedef __bf16 bf16x4 __attribute__((ext_vector_type(4)));
typedef __bf16 bf16x8 __attribute__((ext_vector_type(8)));
typedef float f32x4 __attribute__((ext_vector_type(4)));

#define AS1 __attribute__((address_space(1)))
#define AS3 __attribute__((address_space(3)))
#define GLD16(gptr, lptr) \
  __builtin_amdgcn_global_load_lds((const AS1 unsigned int*)(gptr), \
                                   (AS3 unsigned int*)(lptr), 16, 0, 0)

#define NUM_H   32
#define NUM_KVH 8
#define DH      128
#define SEQ     2048
#define KVLEN   4096
#define HID     4096
#define RSCALE  0.08838834764831845f   // 1/sqrt(128), folded into Q at RoPE time

// ---------------------------------------------------------------------------
// Generic f32 -> bf16 cast, 8 elems/thread.
// ---------------------------------------------------------------------------
__global__ void prep_hs(const float* __restrict__ hs, bf16* __restrict__ out) {
  int tid = blockIdx.x * 256 + threadIdx.x;
  size_t o = (size_t)tid * 8;
  float4 a = *(const float4*)(hs + o);
  float4 b = *(const float4*)(hs + o + 4);
  bf16x8 w = {(bf16)a.x, (bf16)a.y, (bf16)a.z, (bf16)a.w,
              (bf16)b.x, (bf16)b.y, (bf16)b.z, (bf16)b.w};
  *(bf16x8*)(out + o) = w;
}

// Both weights in one launch (blockIdx split).
__global__ void prep_w2(const float* __restrict__ Wq, const float* __restrict__ Wo,
                        bf16* __restrict__ Qo, bf16* __restrict__ Oo) {
  int half = blockIdx.x & 8191;
  const float* src = (blockIdx.x < 8192) ? Wq : Wo;
  bf16* dst = (blockIdx.x < 8192) ? Qo : Oo;
  int tid = half * 256 + threadIdx.x;
  size_t o = (size_t)tid * 8;
  float4 a = *(const float4*)(src + o);
  float4 b = *(const float4*)(src + o + 4);
  bf16x8 w = {(bf16)a.x, (bf16)a.y, (bf16)a.z, (bf16)a.w,
              (bf16)b.x, (bf16)b.y, (bf16)b.z, (bf16)b.w};
  *(bf16x8*)(dst + o) = w;
}

// ---------------------------------------------------------------------------
// K gather+cast: k_cache f32 [blk][kvh][16][128] -> Kg bf16 [kvh][4096][128].
// ---------------------------------------------------------------------------
__global__ void prep_k(const float* __restrict__ kc, const int* __restrict__ bt,
                       bf16* __restrict__ Kg) {
  int tid = blockIdx.x * 256 + threadIdx.x;   // 1M threads
  int c   = tid & 31;
  int j   = (tid >> 5) & 4095;
  int kvh = tid >> 17;
  int blk = bt[j >> 4];
  float4 v = *(const float4*)(kc + (((size_t)blk * NUM_KVH + kvh) * 16 + (j & 15)) * DH + c * 4);
  bf16x4 w = {(bf16)v.x, (bf16)v.y, (bf16)v.z, (bf16)v.w};
  *(bf16x4*)(Kg + ((size_t)kvh * KVLEN + j) * DH + c * 4) = w;
}

// ---------------------------------------------------------------------------
// V gather+cast+transpose via LDS: f32 [blk][kvh][16][128] -> Vt bf16
// [kvh][128][4096].
// ---------------------------------------------------------------------------
__global__ void prep_v(const float* __restrict__ vc, const int* __restrict__ bt,
                       bf16* __restrict__ Vt) {
  __shared__ bf16 T[32][136];                  // +8 pad: conflict-free both ways
  int e2 = blockIdx.x & 127, kvh = blockIdx.x >> 7;
  int t = threadIdx.x;
#pragma unroll
  for (int i = 0; i < 4; i++) {
    int idx = i * 256 + t;                     // 1024 float4 chunks (2 pages)
    int pg  = idx >> 9;
    int pos = (idx >> 5) & 15;
    int c4  = idx & 31;
    int blk = bt[e2 * 2 + pg];
    float4 v = *(const float4*)(vc + (((size_t)blk * NUM_KVH + kvh) * 16 + pos) * DH + c4 * 4);
    bf16x4 w = {(bf16)v.x, (bf16)v.y, (bf16)v.z, (bf16)v.w};
    *(bf16x4*)(&T[pg * 16 + pos][c4 * 4]) = w;
  }
  __syncthreads();
  int d = t & 127, jc = t >> 7;
  bf16 tmp[16];
#pragma unroll
  for (int j = 0; j < 16; j++) tmp[j] = T[jc * 16 + j][d];
  bf16* dst = Vt + ((size_t)kvh * DH + d) * KVLEN + e2 * 32 + jc * 16;
  *(bf16x8*)dst = *(bf16x8*)tmp;
  *(bf16x8*)(dst + 8) = *(bf16x8*)(tmp + 8);
}

// ---------------------------------------------------------------------------
// GEMM v6 (4-phase pipelined, T3+T4 proper): C[M,N] = A_bf16[M,K]*B_bf16[N,K]^T.
// 128x256 tile, BK=64, 512 thr / 8 waves (2M x 4N, 64x64 each), dbuf LDS 96KB,
// grid (M/128)*(N/256) = 256 = 1 block/CU. Each K-tile = 4 phases; phase =
// {stage ONE 16KB unit of tile t+1 (2 GLD16) -> s_barrier (NO drain) ->
//  ds_read one reg-subtile -> 8 MFMA}. Stage units in order A, B-lo, B-hi;
// single vmcnt(2) at phase 0 guarantees all of tile t landed (3 newer units
// may stay in flight). Loads get a 2-4-phase window to land instead of a
// full drain per K-step (the round-2..4 structures' ceiling).
// Safety (1 barrier/phase): unit staged at (t+1,q) overwrites data whose last
// reads finished before a barrier that precedes the stage issue; phase 3
// reads only B so the A-overwrite at phase 0 is safe.
// XCD swizzle bn-major: each XCD's L2 holds its 4MB weight slice.
// ---------------------------------------------------------------------------
template <typename CT>
__global__ __launch_bounds__(512, 2)
void gemm_p4(const bf16* __restrict__ A, const bf16* __restrict__ B,
             CT* __restrict__ C, int M, int N, int K) {
  __shared__ alignas(16) bf16 As[2][128 * 64];   // 16 KB x2
  __shared__ alignas(16) bf16 Bs[2][256 * 64];   // 32 KB x2
  const int nwg = gridDim.x;
  const int q8  = nwg >> 3;
  const int wg  = ((int)blockIdx.x & 7) * q8 + ((int)blockIdx.x >> 3);
  const int nm  = M >> 7;
  const int bn  = wg / nm, bm = wg % nm;         // bn-major within XCD
  const int t = threadIdx.x;                     // 0..511
  const int lane = t & 63, wave = t >> 6;
  const int lid = lane & 15, quad = lane >> 4;
  const int wm = (wave >> 2) * 64, wn = (wave & 3) * 64;
  const bf16* Ab = A + (size_t)bm * 128 * K;
  const bf16* Bb = B + (size_t)bn * 256 * K;
  f32x4 acc[4][4] = {};

  auto stageA = [&](int buf, int k0) {           // 128x64 = 1024 chunks
#pragma unroll
    for (int i = 0; i < 2; i++) {
      int id = i * 512 + t;
      int row = id >> 3, c = id & 7, gc = c ^ (row & 7);
      GLD16(Ab + (size_t)row * K + k0 + gc * 8, &As[buf][id * 8]);
    }
    __builtin_amdgcn_sched_barrier(0);
  };
  auto stageB = [&](int buf, int k0, int half) { // 128x64 half of 256x64
#pragma unroll
    for (int i = 0; i < 2; i++) {
      int id = i * 512 + t;
      int row = half * 128 + (id >> 3), c = id & 7, gc = c ^ (row & 7);
      GLD16(Bb + (size_t)row * K + k0 + gc * 8, &Bs[buf][half * 8192 + id * 8]);
    }
    __builtin_amdgcn_sched_barrier(0);
  };

  // prologue: tile 0 -> buf 0 (6 GLD16 in flight)
  stageA(0, 0); stageB(0, 0, 0); stageB(0, 0, 1);

  const int T = K >> 6;
  int cur = 0;
#pragma unroll 1
  for (int tt = 0; tt < T; tt++) {
    const int kn = (tt + 1 < T ? tt + 1 : tt) * 64;  // last iter: redundant
    const int nxt = cur ^ 1;
    bf16x8 af[4], bfr[2];

    // ---- phase 0: stage A(t+1); vmcnt(2) = tile t fully landed; kk=0 j=0,1
    stageA(nxt, kn);
    asm volatile("s_waitcnt vmcnt(2)" ::: "memory");
    __builtin_amdgcn_s_barrier();
    __builtin_amdgcn_sched_barrier(0);
#pragma unroll
    for (int i = 0; i < 4; i++) {
      int row = wm + i * 16 + lid;
      af[i] = *(const bf16x8*)(&As[cur][row * 64 + (quad ^ (row & 7)) * 8]);
    }
#pragma unroll
    for (int j = 0; j < 2; j++) {
      int row = wn + j * 16 + lid;
      bfr[j] = *(const bf16x8*)(&Bs[cur][row * 64 + (quad ^ (row & 7)) * 8]);
    }
#pragma unroll
    for (int i = 0; i < 4; i++) {
      acc[i][0] = __builtin_amdgcn_mfma_f32_16x16x32_bf16(bfr[0], af[i], acc[i][0], 0, 0, 0);
      acc[i][1] = __builtin_amdgcn_mfma_f32_16x16x32_bf16(bfr[1], af[i], acc[i][1], 0, 0, 0);
    }
    __builtin_amdgcn_sched_barrier(0);

    // ---- phase 1: stage B-lo(t+1); kk=0 j=2,3
    stageB(nxt, kn, 0);
    __builtin_amdgcn_s_barrier();
    __builtin_amdgcn_sched_barrier(0);
#pragma unroll
    for (int j = 0; j < 2; j++) {
      int row = wn + (2 + j) * 16 + lid;
      bfr[j] = *(const bf16x8*)(&Bs[cur][row * 64 + (quad ^ (row & 7)) * 8]);
    }
#pragma unroll
    for (int i = 0; i < 4; i++) {
      acc[i][2] = __builtin_amdgcn_mfma_f32_16x16x32_bf16(bfr[0], af[i], acc[i][2], 0, 0, 0);
      acc[i][3] = __builtin_amdgcn_mfma_f32_16x16x32_bf16(bfr[1], af[i], acc[i][3], 0, 0, 0);
    }
    __builtin_amdgcn_sched_barrier(0);

    // ---- phase 2: stage B-hi(t+1); kk=1 j=0,1
    stageB(nxt, kn, 1);
    __builtin_amdgcn_s_barrier();
    __builtin_amdgcn_sched_barrier(0);
#pragma unroll
    for (int i = 0; i < 4; i++) {
      int row = wm + i * 16 + lid;
      af[i] = *(const bf16x8*)(&As[cur][row * 64 + ((4 + quad) ^ (row & 7)) * 8]);
    }
#pragma unroll
    for (int j = 0; j < 2; j++) {
      int row = wn + j * 16 + lid;
      bfr[j] = *(const bf16x8*)(&Bs[cur][row * 64 + ((4 + quad) ^ (row & 7)) * 8]);
    }
#pragma unroll
    for (int i = 0; i < 4; i++) {
      acc[i][0] = __builtin_amdgcn_mfma_f32_16x16x32_bf16(bfr[0], af[i], acc[i][0], 0, 0, 0);
      acc[i][1] = __builtin_amdgcn_mfma_f32_16x16x32_bf16(bfr[1], af[i], acc[i][1], 0, 0, 0);
    }
    __builtin_amdgcn_sched_barrier(0);

    // ---- phase 3: no stage; kk=1 j=2,3 (reads only B: A-overwrite safe)
    __builtin_amdgcn_s_barrier();
    __builtin_amdgcn_sched_barrier(0);
#pragma unroll
    for (int j = 0; j < 2; j++) {
      int row = wn + (2 + j) * 16 + lid;
      bfr[j] = *(const bf16x8*)(&Bs[cur][row * 64 + ((4 + quad) ^ (row & 7)) * 8]);
    }
#pragma unroll
    for (int i = 0; i < 4; i++) {
      acc[i][2] = __builtin_amdgcn_mfma_f32_16x16x32_bf16(bfr[0], af[i], acc[i][2], 0, 0, 0);
      acc[i][3] = __builtin_amdgcn_mfma_f32_16x16x32_bf16(bfr[1], af[i], acc[i][3], 0, 0, 0);
    }
    __builtin_amdgcn_sched_barrier(0);

    cur = nxt;
  }

  // lane holds C[n = j*16+quad*4+r][m = i*16+lid] -> 4 consecutive n
#pragma unroll
  for (int i = 0; i < 4; i++)
#pragma unroll
    for (int j = 0; j < 4; j++) {
      int m = bm * 128 + wm + i * 16 + lid;
      int n = bn * 256 + wn + j * 16 + quad * 4;
      if constexpr (sizeof(CT) == 4) {
        float4 w = {acc[i][j][0], acc[i][j][1], acc[i][j][2], acc[i][j][3]};
        *(float4*)(&C[(size_t)m * N + n]) = w;
      } else {
        bf16x4 w = {(bf16)acc[i][j][0], (bf16)acc[i][j][1],
                    (bf16)acc[i][j][2], (bf16)acc[i][j][3]};
        *(bf16x4*)(&C[(size_t)m * N + n]) = w;
      }
    }
}

// ---------------------------------------------------------------------------
// RoPE on Q, in place, vectorized.
// ---------------------------------------------------------------------------
__global__ void rope_q(bf16* __restrict__ Q) {
  __shared__ float tcs[64], tsn[64];
  int s = blockIdx.x;
  int t = threadIdx.x;
  if (t < 64) {
    float freq = expf(-(float)t * (logf(10000.f) / 64.f));
    float sn, cs;
    sincosf((float)s * freq, &sn, &cs);
    tsn[t] = sn; tcs[t] = cs;
  }
  __syncthreads();
  int h = t >> 3, d0 = (t & 7) * 8;            // 32 heads x 8-elem chunks
  bf16* ptr = Q + (size_t)s * HID + h * DH;
  bf16x8 lo = *(bf16x8*)(ptr + d0);
  bf16x8 hi = *(bf16x8*)(ptr + 64 + d0);
  bf16x8 olo, ohi;
#pragma unroll
  for (int e = 0; e < 8; e++) {
    float cs = tcs[d0 + e], sn = tsn[d0 + e];
    float q0 = (float)lo[e], q1 = (float)hi[e];
    olo[e] = (bf16)((q0 * cs - q1 * sn) * RSCALE);
    ohi[e] = (bf16)((q1 * cs + q0 * sn) * RSCALE);
  }
  *(bf16x8*)(ptr + d0) = olo;
  *(bf16x8*)(ptr + 64 + d0) = ohi;
}

// ---------------------------------------------------------------------------
// Flash attention v3 (unchanged from round 4, for attribution).
// ---------------------------------------------------------------------------
__global__ __launch_bounds__(256, 2)
void attn(bf16* __restrict__ Q,                 // [2048][4096] bf16, in-place ctx
          const bf16* __restrict__ Kg,          // [kvh][4096][128]
          const bf16* __restrict__ Vt) {        // [kvh][128][4096]
  __shared__ alignas(16) bf16 Ks[2][64 * 128]; // [kv][d], chunk-swizzled
  __shared__ alignas(16) bf16 Vs[2][128 * 64]; // [d][kv], chunk-swizzled
  __shared__ alignas(16) bf16 Ps[4][2][1024];  // [q=16][kv=64], swizzled
  const int bid = ((int)blockIdx.x & 7) * 64 + ((int)blockIdx.x >> 3);  // XCD swz
  const int h = bid >> 4, qt2 = bid & 15;      // 128 q rows per block
  const int kvh = h >> 2;
  const int t = threadIdx.x;
  const int wave = t >> 6, lane = t & 63;
  const int lid = lane & 15, quad = lane >> 4;

  bf16x8 qf[2][4];
#pragma unroll
  for (int x = 0; x < 2; x++) {
    const bf16* qb = Q + (size_t)(qt2 * 128 + x * 64 + wave * 16 + lid) * HID + h * DH;
#pragma unroll
    for (int kc = 0; kc < 4; kc++) qf[x][kc] = *(const bf16x8*)(qb + kc * 32 + quad * 8);
  }
  const bf16* Kh = Kg + (size_t)kvh * KVLEN * DH;
  const bf16* Vh = Vt + (size_t)kvh * DH * KVLEN;
  f32x4 acc_o[2][8] = {};
  f32x4 lsum[2] = {};
  const bf16 one = (bf16)1.0f;
  const bf16x8 ones = {one, one, one, one, one, one, one, one};

  auto stage = [&](int buf, int kv0) {
#pragma unroll
    for (int i = 0; i < 4; i++) {   // K tile: 1024 16B chunks
      int id = i * 256 + t;
      int row = id >> 4, cs = id & 15;
      int gc = cs ^ (row & 7);
      GLD16(Kh + (size_t)(kv0 + row) * DH + gc * 8, &Ks[buf][id * 8]);
    }
#pragma unroll
    for (int i = 0; i < 4; i++) {   // V tile (transposed layout)
      int id = i * 256 + t;
      int d = id >> 3, cs = id & 7;
      int gc = cs ^ (d & 7);
      GLD16(Vh + (size_t)d * KVLEN + kv0 + gc * 8, &Vs[buf][id * 8]);
    }
  };

  stage(0, 0);
  int cur = 0;
#pragma unroll 1
  for (int kv0 = 0; kv0 < KVLEN; kv0 += 64) {
    if (kv0 + 64 < KVLEN) {
      stage(cur ^ 1, kv0 + 64);    // prefetch next tile (8 GLD16 in flight)
      asm volatile("s_waitcnt vmcnt(8)" ::: "memory");  // cur's 8 landed
    } else {
      asm volatile("s_waitcnt vmcnt(0)" ::: "memory");  // tail: drain
    }
    __builtin_amdgcn_s_barrier();
    __builtin_amdgcn_sched_barrier(0);

    // S^T = K Q^T (swapped): lane holds S[q=lid][kv = n*16+quad*4+r]
    f32x4 sv[2][4];
#pragma unroll
    for (int n = 0; n < 4; n++) {
      f32x4 s0 = {}, s1 = {};
      int row = n * 16 + lid;
#pragma unroll
      for (int kc = 0; kc < 4; kc++) {
        int cs = (kc * 4 + quad) ^ (row & 7);
        bf16x8 kf = *(const bf16x8*)(&Ks[cur][row * DH + cs * 8]);
        s0 = __builtin_amdgcn_mfma_f32_16x16x32_bf16(kf, qf[0][kc], s0, 0, 0, 0);
        s1 = __builtin_amdgcn_mfma_f32_16x16x32_bf16(kf, qf[1][kc], s1, 0, 0, 0);
      }
      sv[0][n] = s0; sv[1][n] = s1;
    }

    // P = exp(S): packed b64 writes, 16B-chunk swizzle c ^= (lid&7).
#pragma unroll
    for (int x = 0; x < 2; x++)
#pragma unroll
      for (int n = 0; n < 4; n++) {
        bf16x4 w = {(bf16)__expf(sv[x][n][0]), (bf16)__expf(sv[x][n][1]),
                    (bf16)__expf(sv[x][n][2]), (bf16)__expf(sv[x][n][3])};
        int c = (2 * n + (quad >> 1)) ^ (lid & 7);
        *(bf16x4*)(&Ps[wave][x][lid * 64 + c * 8 + (quad & 1) * 4]) = w;
      }
    // wave-private Ps: lgkmcnt ordering suffices, no barrier

    bf16x8 pf[2][2];
#pragma unroll
    for (int x = 0; x < 2; x++)
#pragma unroll
      for (int kvc = 0; kvc < 2; kvc++) {
        int c = (kvc * 4 + quad) ^ (lid & 7);
        pf[x][kvc] = *(const bf16x8*)(&Ps[wave][x][lid * 64 + c * 8]);
      }

    // l += 1 . P^T : rowsum(q=lid) lands in ALL 4 regs
#pragma unroll
    for (int x = 0; x < 2; x++) {
      lsum[x] = __builtin_amdgcn_mfma_f32_16x16x32_bf16(ones, pf[x][0], lsum[x], 0, 0, 0);
      lsum[x] = __builtin_amdgcn_mfma_f32_16x16x32_bf16(ones, pf[x][1], lsum[x], 0, 0, 0);
    }

    // O^T += V^T P^T (swapped): lane holds O[d = dt*16+quad*4+r][q=lid]
#pragma unroll
    for (int dt = 0; dt < 8; dt++) {
      int d = dt * 16 + lid;
#pragma unroll
      for (int kvc = 0; kvc < 2; kvc++) {
        int cs = (kvc * 4 + quad) ^ (d & 7);
        bf16x8 vf = *(const bf16x8*)(&Vs[cur][d * 64 + cs * 8]);
        acc_o[0][dt] = __builtin_amdgcn_mfma_f32_16x16x32_bf16(vf, pf[0][kvc], acc_o[0][dt], 0, 0, 0);
        acc_o[1][dt] = __builtin_amdgcn_mfma_f32_16x16x32_bf16(vf, pf[1][kvc], acc_o[1][dt], 0, 0, 0);
      }
    }

    __builtin_amdgcn_sched_barrier(0);
    asm volatile("s_waitcnt lgkmcnt(0)" ::: "memory");  // LDS reads retired
    __builtin_amdgcn_s_barrier();
    cur ^= 1;
  }

  // epilogue: lane writes 4 consecutive d per (x,dt) -> 8B stores
#pragma unroll
  for (int x = 0; x < 2; x++) {
    float rinv = 1.0f / lsum[x][0];
    int q = qt2 * 128 + x * 64 + wave * 16 + lid;
#pragma unroll
    for (int dt = 0; dt < 8; dt++) {
      bf16x4 w = {(bf16)(acc_o[x][dt][0] * rinv), (bf16)(acc_o[x][dt][1] * rinv),
                  (bf16)(acc_o[x][dt][2] * rinv), (bf16)(acc_o[x][dt][3] * rinv)};
      *(bf16x4*)(&Q[(size_t)q * HID + h * DH + dt * 16 + quad * 4]) = w;
    }
  }
}

// ---------------------------------------------------------------------------
// GEMM v2 (fallback when workspace too small for bf16 weights).
// ---------------------------------------------------------------------------
template <typename CT>
__global__ __launch_bounds__(512, 2)
void gemm_bt2(const bf16* __restrict__ A, const float* __restrict__ B,
              CT* __restrict__ C, int M, int N, int K) {
  __shared__ alignas(16) bf16 As[2][128 * 64];
  __shared__ alignas(16) bf16 Bs[2][256 * 64];
  const int nb = N >> 8;
  const int bm = (int)blockIdx.x / nb;
  const int bn = (int)blockIdx.x % nb;
  const int t = threadIdx.x;
  const int lane = t & 63, wave = t >> 6;
  const int lid = lane & 15, quad = lane >> 4;
  const int wm = (wave >> 2) * 64, wn = (wave & 3) * 64;
  const bf16*  Ab = A + (size_t)bm * 128 * K;
  const float* Bb = B + (size_t)bn * 256 * K;
  f32x4 acc[4][4] = {};
  float4 breg[4][2];

  auto issueA = [&](int buf, int k0) {
#pragma unroll
    for (int i = 0; i < 2; i++) {
      int id = i * 512 + t;
      int row = id >> 3, c = id & 7;
      int gc = c ^ (row & 7);
      GLD16(Ab + (size_t)row * K + k0 + gc * 8, &As[buf][id * 8]);
    }
  };
  auto loadB = [&](int k0) {
#pragma unroll
    for (int i = 0; i < 4; i++) {
      int id = i * 512 + t;
      int row = id >> 3, c = id & 7;
      const float* src = Bb + (size_t)row * K + k0 + c * 8;
      breg[i][0] = *(const float4*)(src);
      breg[i][1] = *(const float4*)(src + 4);
    }
  };
  auto writeB = [&](int buf) {
#pragma unroll
    for (int i = 0; i < 4; i++) {
      int id = i * 512 + t;
      int row = id >> 3, c = id & 7;
      int sc = c ^ (row & 7);
      float4 u = breg[i][0], v = breg[i][1];
      bf16x8 w = {(bf16)u.x, (bf16)u.y, (bf16)u.z, (bf16)u.w,
                  (bf16)v.x, (bf16)v.y, (bf16)v.z, (bf16)v.w};
      *(bf16x8*)(&Bs[buf][row * 64 + sc * 8]) = w;
    }
  };
  auto compute = [&](int buf) {
#pragma unroll
    for (int kk = 0; kk < 2; kk++) {
      bf16x8 af[4], bfr[4];
#pragma unroll
      for (int i = 0; i < 4; i++) {
        int row = wm + i * 16 + lid;
        af[i] = *(const bf16x8*)(&As[buf][row * 64 + ((kk * 4 + quad) ^ (row & 7)) * 8]);
      }
#pragma unroll
      for (int j = 0; j < 4; j++) {
        int row = wn + j * 16 + lid;
        bfr[j] = *(const bf16x8*)(&Bs[buf][row * 64 + ((kk * 4 + quad) ^ (row & 7)) * 8]);
      }
#pragma unroll
      for (int i = 0; i < 4; i++)
#pragma unroll
        for (int j = 0; j < 4; j++)
          acc[i][j] = __builtin_amdgcn_mfma_f32_16x16x32_bf16(af[i], bfr[j], acc[i][j], 0, 0, 0);
    }
  };

  issueA(0, 0);
  loadB(0);
  writeB(0);
  __syncthreads();

  int cur = 0;
#pragma unroll 1
  for (int k0 = 64; k0 < K; k0 += 64) {
    issueA(cur ^ 1, k0);
    loadB(k0);
    __builtin_amdgcn_sched_barrier(0);
    compute(cur);
    __builtin_amdgcn_sched_barrier(0);
    writeB(cur ^ 1);
    __syncthreads();
    cur ^= 1;
  }
  compute(cur);

#pragma unroll
  for (int i = 0; i < 4; i++)
#pragma unroll
    for (int j = 0; j < 4; j++)
#pragma unroll
      for (int r = 0; r < 4; r++) {
        int m = bm * 128 + wm + i * 16 + quad * 4 + r;
        int n = bn * 256 + wn + j * 16 + lid;
        C[(size_t)m * N + n] = (CT)acc[i][j][r];
      }
}

// ---------------------------------------------------------------------------
extern "C" void kernel_launch(void* const* d_in, const int* in_sizes, int n_in,
                              void* d_out, int out_size, void* d_ws, size_t ws_size,
                              hipStream_t stream) {
  const float* hs  = (const float*)d_in[0];
  const float* kca = (const float*)d_in[1];
  const float* vca = (const float*)d_in[2];
  const float* Wq  = (const float*)d_in[3];
  const float* Wo  = (const float*)d_in[4];
  const int*   bt  = (const int*)d_in[5];
  float* out = (float*)d_out;

  // Scratch plan:
  //   ws[0..16MiB)      : Qlin bf16 -> rope in place -> ctx in place
  //   ws[16..48MiB)     : Wq_bf bf16 [4096][4096]   (big-ws path)
  //   ws[48..80MiB)     : Wo_bf bf16 [4096][4096]   (big-ws path)
  //   d_out[0..8MiB)    : Kg bf16 [8][4096][128]    (dead before oproj)
  //   d_out[8..16MiB)   : Vt bf16 [8][128][4096]    (dead before oproj)
  //   d_out[16..32MiB)  : hs_bf bf16 [2048][4096]   (dead after qproj)
  bf16* Qlin  = (bf16*)d_ws;
  bf16* Kg    = (bf16*)d_out;
  bf16* Vt    = (bf16*)((char*)d_out + (8u << 20));
  bf16* hs_bf = (bf16*)((char*)d_out + (16u << 20));

  prep_k<<<4096, 256, 0, stream>>>(kca, bt, Kg);
  prep_v<<<1024, 256, 0, stream>>>(vca, bt, Vt);
  prep_hs<<<4096, 256, 0, stream>>>(hs, hs_bf);

  if (ws_size >= (80u << 20)) {
    bf16* Wq_bf = (bf16*)((char*)d_ws + (16u << 20));
    bf16* Wo_bf = (bf16*)((char*)d_ws + (48u << 20));
    prep_w2<<<16384, 256, 0, stream>>>(Wq, Wo, Wq_bf, Wo_bf);
    gemm_p4<bf16><<<256, 512, 0, stream>>>(hs_bf, Wq_bf, Qlin, SEQ, HID, HID);
    rope_q<<<SEQ, 256, 0, stream>>>(Qlin);
    attn<<<512, 256, 0, stream>>>(Qlin, Kg, Vt);
    gemm_p4<float><<<256, 512, 0, stream>>>(Qlin, Wo_bf, out, SEQ, HID, HID);
  } else {
    gemm_bt2<bf16><<<256, 512, 0, stream>>>(hs_bf, Wq, Qlin, SEQ, HID, HID);
    rope_q<<<SEQ, 256, 0, stream>>>(Qlin);
    attn<<<512, 256, 0, stream>>>(Qlin, Kg, Vt);
    gemm_bt2<float><<<256, 512, 0, stream>>>(Qlin, Wo, out, SEQ, HID, HID);
  }
}

// Round 6
// 513.403 us; speedup vs baseline: 1.1414x; 1.1414x over previous
//
#include <hip/hip_runtime.h>
#include <hip/hip_bf16.h>

typedef __bf16 bf16;
typedef __bf16 bf16x4 __attribute__((ext_vector_type(4)));
typedef __bf16 bf16x8 __attribute__((ext_vector_type(8)));
typedef float f32x4 __attribute__((ext_vector_type(4)));

#define AS1 __attribute__((address_space(1)))
#define AS3 __attribute__((address_space(3)))
#define GLD16(gptr, lptr) \
  __builtin_amdgcn_global_load_lds((const AS1 unsigned int*)(gptr), \
                                   (AS3 unsigned int*)(lptr), 16, 0, 0)

#define NUM_H   32
#define NUM_KVH 8
#define DH      128
#define SEQ     2048
#define KVLEN   4096
#define HID     4096
#define RSCALE  0.08838834764831845f   // 1/sqrt(128), folded into Q at RoPE time

// ---------------------------------------------------------------------------
// Generic f32 -> bf16 cast, 8 elems/thread.
// ---------------------------------------------------------------------------
__global__ void prep_hs(const float* __restrict__ hs, bf16* __restrict__ out) {
  int tid = blockIdx.x * 256 + threadIdx.x;
  size_t o = (size_t)tid * 8;
  float4 a = *(const float4*)(hs + o);
  float4 b = *(const float4*)(hs + o + 4);
  bf16x8 w = {(bf16)a.x, (bf16)a.y, (bf16)a.z, (bf16)a.w,
              (bf16)b.x, (bf16)b.y, (bf16)b.z, (bf16)b.w};
  *(bf16x8*)(out + o) = w;
}

// Both weights in one launch (blockIdx split).
__global__ void prep_w2(const float* __restrict__ Wq, const float* __restrict__ Wo,
                        bf16* __restrict__ Qo, bf16* __restrict__ Oo) {
  int half = blockIdx.x & 8191;
  const float* src = (blockIdx.x < 8192) ? Wq : Wo;
  bf16* dst = (blockIdx.x < 8192) ? Qo : Oo;
  int tid = half * 256 + threadIdx.x;
  size_t o = (size_t)tid * 8;
  float4 a = *(const float4*)(src + o);
  float4 b = *(const float4*)(src + o + 4);
  bf16x8 w = {(bf16)a.x, (bf16)a.y, (bf16)a.z, (bf16)a.w,
              (bf16)b.x, (bf16)b.y, (bf16)b.z, (bf16)b.w};
  *(bf16x8*)(dst + o) = w;
}

// ---------------------------------------------------------------------------
// K gather+cast: k_cache f32 [blk][kvh][16][128] -> Kg bf16 [kvh][4096][128].
// ---------------------------------------------------------------------------
__global__ void prep_k(const float* __restrict__ kc, const int* __restrict__ bt,
                       bf16* __restrict__ Kg) {
  int tid = blockIdx.x * 256 + threadIdx.x;   // 1M threads
  int c   = tid & 31;
  int j   = (tid >> 5) & 4095;
  int kvh = tid >> 17;
  int blk = bt[j >> 4];
  float4 v = *(const float4*)(kc + (((size_t)blk * NUM_KVH + kvh) * 16 + (j & 15)) * DH + c * 4);
  bf16x4 w = {(bf16)v.x, (bf16)v.y, (bf16)v.z, (bf16)v.w};
  *(bf16x4*)(Kg + ((size_t)kvh * KVLEN + j) * DH + c * 4) = w;
}

// ---------------------------------------------------------------------------
// V gather+cast+transpose via LDS: f32 [blk][kvh][16][128] -> Vt bf16
// [kvh][128][4096].
// ---------------------------------------------------------------------------
__global__ void prep_v(const float* __restrict__ vc, const int* __restrict__ bt,
                       bf16* __restrict__ Vt) {
  __shared__ bf16 T[32][136];                  // +8 pad: conflict-free both ways
  int e2 = blockIdx.x & 127, kvh = blockIdx.x >> 7;
  int t = threadIdx.x;
#pragma unroll
  for (int i = 0; i < 4; i++) {
    int idx = i * 256 + t;                     // 1024 float4 chunks (2 pages)
    int pg  = idx >> 9;
    int pos = (idx >> 5) & 15;
    int c4  = idx & 31;
    int blk = bt[e2 * 2 + pg];
    float4 v = *(const float4*)(vc + (((size_t)blk * NUM_KVH + kvh) * 16 + pos) * DH + c4 * 4);
    bf16x4 w = {(bf16)v.x, (bf16)v.y, (bf16)v.z, (bf16)v.w};
    *(bf16x4*)(&T[pg * 16 + pos][c4 * 4]) = w;
  }
  __syncthreads();
  int d = t & 127, jc = t >> 7;
  bf16 tmp[16];
#pragma unroll
  for (int j = 0; j < 16; j++) tmp[j] = T[jc * 16 + j][d];
  bf16* dst = Vt + ((size_t)kvh * DH + d) * KVLEN + e2 * 32 + jc * 16;
  *(bf16x8*)dst = *(bf16x8*)tmp;
  *(bf16x8*)(dst + 8) = *(bf16x8*)(tmp + 8);
}

// ---------------------------------------------------------------------------
// GEMM v7: C[M,N] = A_bf16[M,K] * B_bf16[N,K]^T. Both operands via GLD16.
// 128x128 tile, BK=64, dbuf LDS 64 KB -> 2 blocks/CU, BUT 512 threads /
// 8 waves (2M x 4N -> 64x32 per wave, acc 32 VGPR, ~86 total, capped at
// 128 by launch_bounds) -> 16 waves/CU (4/SIMD). The rounds-3..5 plateau
// was OCCUPANCY (8 waves/CU = 2/SIMD): every schedule tweak at that
// occupancy was neutral (matches m131-m140); m97's 874 TF came from
// 12 waves/CU implicit wave-level overlap (m114). This doubles TLP with
// the tile/LDS/swizzle/counted-vmcnt structure unchanged.
// ---------------------------------------------------------------------------
template <typename CT>
__global__ __launch_bounds__(512, 4)
void gemm_w8(const bf16* __restrict__ A, const bf16* __restrict__ B,
             CT* __restrict__ C, int M, int N, int K) {
  __shared__ alignas(16) bf16 As[2][128 * 64];   // 16 KB x2
  __shared__ alignas(16) bf16 Bs[2][128 * 64];   // 16 KB x2
  const int nwg = gridDim.x;
  const int q8  = nwg >> 3;
  const int wg  = ((int)blockIdx.x & 7) * q8 + ((int)blockIdx.x >> 3);
  const int nb = N >> 7;
  const int bm = wg / nb;
  const int bn = wg % nb;
  const int t = threadIdx.x;                     // 0..511
  const int lane = t & 63, wave = t >> 6;        // 8 waves
  const int lid = lane & 15, quad = lane >> 4;
  const int wm = (wave >> 2) * 64, wn = (wave & 3) * 32;   // 2M x 4N
  const bf16* Ab = A + (size_t)bm * 128 * K;
  const bf16* Bb = B + (size_t)bn * 128 * K;
  f32x4 acc[4][2] = {};

  auto stage = [&](int buf, int k0) {            // 4 GLD16/thread
#pragma unroll
    for (int i = 0; i < 2; i++) {                // A: 128x64 = 1024 chunks
      int id = i * 512 + t;
      int row = id >> 3, c = id & 7;
      int gc = c ^ (row & 7);
      GLD16(Ab + (size_t)row * K + k0 + gc * 8, &As[buf][id * 8]);
    }
#pragma unroll
    for (int i = 0; i < 2; i++) {                // B: 128x64 = 1024 chunks
      int id = i * 512 + t;
      int row = id >> 3, c = id & 7;
      int gc = c ^ (row & 7);
      GLD16(Bb + (size_t)row * K + k0 + gc * 8, &Bs[buf][id * 8]);
    }
  };
  auto compute = [&](int buf) {
#pragma unroll
    for (int kk = 0; kk < 2; kk++) {
      bf16x8 af[4], bfr[2];
#pragma unroll
      for (int i = 0; i < 4; i++) {
        int row = wm + i * 16 + lid;
        af[i] = *(const bf16x8*)(&As[buf][row * 64 + ((kk * 4 + quad) ^ (row & 7)) * 8]);
      }
#pragma unroll
      for (int j = 0; j < 2; j++) {
        int row = wn + j * 16 + lid;
        bfr[j] = *(const bf16x8*)(&Bs[buf][row * 64 + ((kk * 4 + quad) ^ (row & 7)) * 8]);
      }
#pragma unroll
      for (int i = 0; i < 4; i++)
#pragma unroll
        for (int j = 0; j < 2; j++)   // SWAPPED: C^T fragment, n in regs
          acc[i][j] = __builtin_amdgcn_mfma_f32_16x16x32_bf16(bfr[j], af[i], acc[i][j], 0, 0, 0);
    }
  };

  stage(0, 0);
  int cur = 0;
#pragma unroll 1
  for (int k0 = 64; k0 < K; k0 += 64) {
    stage(cur ^ 1, k0);            // 4 more GLD16 in flight
    asm volatile("s_waitcnt vmcnt(4)" ::: "memory");   // cur's 4 landed
    __builtin_amdgcn_s_barrier();
    __builtin_amdgcn_sched_barrier(0);
    compute(cur);
    __builtin_amdgcn_sched_barrier(0);
    asm volatile("s_waitcnt lgkmcnt(0)" ::: "memory"); // ds_reads retired
    __builtin_amdgcn_s_barrier();
    cur ^= 1;
  }
  asm volatile("s_waitcnt vmcnt(0)" ::: "memory");
  __builtin_amdgcn_s_barrier();
  __builtin_amdgcn_sched_barrier(0);
  compute(cur);

  // lane holds C[n = wn+j*16+quad*4+r][m = wm+i*16+lid] -> 4 consecutive n
#pragma unroll
  for (int i = 0; i < 4; i++)
#pragma unroll
    for (int j = 0; j < 2; j++) {
      int m = bm * 128 + wm + i * 16 + lid;
      int n = bn * 128 + wn + j * 16 + quad * 4;
      if constexpr (sizeof(CT) == 4) {
        float4 w = {acc[i][j][0], acc[i][j][1], acc[i][j][2], acc[i][j][3]};
        *(float4*)(&C[(size_t)m * N + n]) = w;
      } else {
        bf16x4 w = {(bf16)acc[i][j][0], (bf16)acc[i][j][1],
                    (bf16)acc[i][j][2], (bf16)acc[i][j][3]};
        *(bf16x4*)(&C[(size_t)m * N + n]) = w;
      }
    }
}

// ---------------------------------------------------------------------------
// RoPE on Q, in place, vectorized.
// ---------------------------------------------------------------------------
__global__ void rope_q(bf16* __restrict__ Q) {
  __shared__ float tcs[64], tsn[64];
  int s = blockIdx.x;
  int t = threadIdx.x;
  if (t < 64) {
    float freq = expf(-(float)t * (logf(10000.f) / 64.f));
    float sn, cs;
    sincosf((float)s * freq, &sn, &cs);
    tsn[t] = sn; tcs[t] = cs;
  }
  __syncthreads();
  int h = t >> 3, d0 = (t & 7) * 8;            // 32 heads x 8-elem chunks
  bf16* ptr = Q + (size_t)s * HID + h * DH;
  bf16x8 lo = *(bf16x8*)(ptr + d0);
  bf16x8 hi = *(bf16x8*)(ptr + 64 + d0);
  bf16x8 olo, ohi;
#pragma unroll
  for (int e = 0; e < 8; e++) {
    float cs = tcs[d0 + e], sn = tsn[d0 + e];
    float q0 = (float)lo[e], q1 = (float)hi[e];
    olo[e] = (bf16)((q0 * cs - q1 * sn) * RSCALE);
    ohi[e] = (bf16)((q1 * cs + q0 * sn) * RSCALE);
  }
  *(bf16x8*)(ptr + d0) = olo;
  *(bf16x8*)(ptr + 64 + d0) = ohi;
}

// ---------------------------------------------------------------------------
// Flash attention v3 (byte-identical to round 4, for attribution).
// ---------------------------------------------------------------------------
__global__ __launch_bounds__(256, 2)
void attn(bf16* __restrict__ Q,                 // [2048][4096] bf16, in-place ctx
          const bf16* __restrict__ Kg,          // [kvh][4096][128]
          const bf16* __restrict__ Vt) {        // [kvh][128][4096]
  __shared__ alignas(16) bf16 Ks[2][64 * 128]; // [kv][d], chunk-swizzled
  __shared__ alignas(16) bf16 Vs[2][128 * 64]; // [d][kv], chunk-swizzled
  __shared__ alignas(16) bf16 Ps[4][2][1024];  // [q=16][kv=64], swizzled
  const int bid = ((int)blockIdx.x & 7) * 64 + ((int)blockIdx.x >> 3);  // XCD swz
  const int h = bid >> 4, qt2 = bid & 15;      // 128 q rows per block
  const int kvh = h >> 2;
  const int t = threadIdx.x;
  const int wave = t >> 6, lane = t & 63;
  const int lid = lane & 15, quad = lane >> 4;

  bf16x8 qf[2][4];
#pragma unroll
  for (int x = 0; x < 2; x++) {
    const bf16* qb = Q + (size_t)(qt2 * 128 + x * 64 + wave * 16 + lid) * HID + h * DH;
#pragma unroll
    for (int kc = 0; kc < 4; kc++) qf[x][kc] = *(const bf16x8*)(qb + kc * 32 + quad * 8);
  }
  const bf16* Kh = Kg + (size_t)kvh * KVLEN * DH;
  const bf16* Vh = Vt + (size_t)kvh * DH * KVLEN;
  f32x4 acc_o[2][8] = {};
  f32x4 lsum[2] = {};
  const bf16 one = (bf16)1.0f;
  const bf16x8 ones = {one, one, one, one, one, one, one, one};

  auto stage = [&](int buf, int kv0) {
#pragma unroll
    for (int i = 0; i < 4; i++) {   // K tile: 1024 16B chunks
      int id = i * 256 + t;
      int row = id >> 4, cs = id & 15;
      int gc = cs ^ (row & 7);
      GLD16(Kh + (size_t)(kv0 + row) * DH + gc * 8, &Ks[buf][id * 8]);
    }
#pragma unroll
    for (int i = 0; i < 4; i++) {   // V tile (transposed layout)
      int id = i * 256 + t;
      int d = id >> 3, cs = id & 7;
      int gc = cs ^ (d & 7);
      GLD16(Vh + (size_t)d * KVLEN + kv0 + gc * 8, &Vs[buf][id * 8]);
    }
  };

  stage(0, 0);
  int cur = 0;
#pragma unroll 1
  for (int kv0 = 0; kv0 < KVLEN; kv0 += 64) {
    if (kv0 + 64 < KVLEN) {
      stage(cur ^ 1, kv0 + 64);    // prefetch next tile (8 GLD16 in flight)
      asm volatile("s_waitcnt vmcnt(8)" ::: "memory");  // cur's 8 landed
    } else {
      asm volatile("s_waitcnt vmcnt(0)" ::: "memory");  // tail: drain
    }
    __builtin_amdgcn_s_barrier();
    __builtin_amdgcn_sched_barrier(0);

    // S^T = K Q^T (swapped): lane holds S[q=lid][kv = n*16+quad*4+r]
    f32x4 sv[2][4];
#pragma unroll
    for (int n = 0; n < 4; n++) {
      f32x4 s0 = {}, s1 = {};
      int row = n * 16 + lid;
#pragma unroll
      for (int kc = 0; kc < 4; kc++) {
        int cs = (kc * 4 + quad) ^ (row & 7);
        bf16x8 kf = *(const bf16x8*)(&Ks[cur][row * DH + cs * 8]);
        s0 = __builtin_amdgcn_mfma_f32_16x16x32_bf16(kf, qf[0][kc], s0, 0, 0, 0);
        s1 = __builtin_amdgcn_mfma_f32_16x16x32_bf16(kf, qf[1][kc], s1, 0, 0, 0);
      }
      sv[0][n] = s0; sv[1][n] = s1;
    }

    // P = exp(S): packed b64 writes, 16B-chunk swizzle c ^= (lid&7).
#pragma unroll
    for (int x = 0; x < 2; x++)
#pragma unroll
      for (int n = 0; n < 4; n++) {
        bf16x4 w = {(bf16)__expf(sv[x][n][0]), (bf16)__expf(sv[x][n][1]),
                    (bf16)__expf(sv[x][n][2]), (bf16)__expf(sv[x][n][3])};
        int c = (2 * n + (quad >> 1)) ^ (lid & 7);
        *(bf16x4*)(&Ps[wave][x][lid * 64 + c * 8 + (quad & 1) * 4]) = w;
      }
    // wave-private Ps: lgkmcnt ordering suffices, no barrier

    bf16x8 pf[2][2];
#pragma unroll
    for (int x = 0; x < 2; x++)
#pragma unroll
      for (int kvc = 0; kvc < 2; kvc++) {
        int c = (kvc * 4 + quad) ^ (lid & 7);
        pf[x][kvc] = *(const bf16x8*)(&Ps[wave][x][lid * 64 + c * 8]);
      }

    // l += 1 . P^T : rowsum(q=lid) lands in ALL 4 regs
#pragma unroll
    for (int x = 0; x < 2; x++) {
      lsum[x] = __builtin_amdgcn_mfma_f32_16x16x32_bf16(ones, pf[x][0], lsum[x], 0, 0, 0);
      lsum[x] = __builtin_amdgcn_mfma_f32_16x16x32_bf16(ones, pf[x][1], lsum[x], 0, 0, 0);
    }

    // O^T += V^T P^T (swapped): lane holds O[d = dt*16+quad*4+r][q=lid]
#pragma unroll
    for (int dt = 0; dt < 8; dt++) {
      int d = dt * 16 + lid;
#pragma unroll
      for (int kvc = 0; kvc < 2; kvc++) {
        int cs = (kvc * 4 + quad) ^ (d & 7);
        bf16x8 vf = *(const bf16x8*)(&Vs[cur][d * 64 + cs * 8]);
        acc_o[0][dt] = __builtin_amdgcn_mfma_f32_16x16x32_bf16(vf, pf[0][kvc], acc_o[0][dt], 0, 0, 0);
        acc_o[1][dt] = __builtin_amdgcn_mfma_f32_16x16x32_bf16(vf, pf[1][kvc], acc_o[1][dt], 0, 0, 0);
      }
    }

    __builtin_amdgcn_sched_barrier(0);
    asm volatile("s_waitcnt lgkmcnt(0)" ::: "memory");  // LDS reads retired
    __builtin_amdgcn_s_barrier();
    cur ^= 1;
  }

  // epilogue: lane writes 4 consecutive d per (x,dt) -> 8B stores
#pragma unroll
  for (int x = 0; x < 2; x++) {
    float rinv = 1.0f / lsum[x][0];
    int q = qt2 * 128 + x * 64 + wave * 16 + lid;
#pragma unroll
    for (int dt = 0; dt < 8; dt++) {
      bf16x4 w = {(bf16)(acc_o[x][dt][0] * rinv), (bf16)(acc_o[x][dt][1] * rinv),
                  (bf16)(acc_o[x][dt][2] * rinv), (bf16)(acc_o[x][dt][3] * rinv)};
      *(bf16x4*)(&Q[(size_t)q * HID + h * DH + dt * 16 + quad * 4]) = w;
    }
  }
}

// ---------------------------------------------------------------------------
// GEMM v2 (fallback when workspace too small for bf16 weights).
// ---------------------------------------------------------------------------
template <typename CT>
__global__ __launch_bounds__(512, 2)
void gemm_bt2(const bf16* __restrict__ A, const float* __restrict__ B,
              CT* __restrict__ C, int M, int N, int K) {
  __shared__ alignas(16) bf16 As[2][128 * 64];
  __shared__ alignas(16) bf16 Bs[2][256 * 64];
  const int nb = N >> 8;
  const int bm = (int)blockIdx.x / nb;
  const int bn = (int)blockIdx.x % nb;
  const int t = threadIdx.x;
  const int lane = t & 63, wave = t >> 6;
  const int lid = lane & 15, quad = lane >> 4;
  const int wm = (wave >> 2) * 64, wn = (wave & 3) * 64;
  const bf16*  Ab = A + (size_t)bm * 128 * K;
  const float* Bb = B + (size_t)bn * 256 * K;
  f32x4 acc[4][4] = {};
  float4 breg[4][2];

  auto issueA = [&](int buf, int k0) {
#pragma unroll
    for (int i = 0; i < 2; i++) {
      int id = i * 512 + t;
      int row = id >> 3, c = id & 7;
      int gc = c ^ (row & 7);
      GLD16(Ab + (size_t)row * K + k0 + gc * 8, &As[buf][id * 8]);
    }
  };
  auto loadB = [&](int k0) {
#pragma unroll
    for (int i = 0; i < 4; i++) {
      int id = i * 512 + t;
      int row = id >> 3, c = id & 7;
      const float* src = Bb + (size_t)row * K + k0 + c * 8;
      breg[i][0] = *(const float4*)(src);
      breg[i][1] = *(const float4*)(src + 4);
    }
  };
  auto writeB = [&](int buf) {
#pragma unroll
    for (int i = 0; i < 4; i++) {
      int id = i * 512 + t;
      int row = id >> 3, c = id & 7;
      int sc = c ^ (row & 7);
      float4 u = breg[i][0], v = breg[i][1];
      bf16x8 w = {(bf16)u.x, (bf16)u.y, (bf16)u.z, (bf16)u.w,
                  (bf16)v.x, (bf16)v.y, (bf16)v.z, (bf16)v.w};
      *(bf16x8*)(&Bs[buf][row * 64 + sc * 8]) = w;
    }
  };
  auto compute = [&](int buf) {
#pragma unroll
    for (int kk = 0; kk < 2; kk++) {
      bf16x8 af[4], bfr[4];
#pragma unroll
      for (int i = 0; i < 4; i++) {
        int row = wm + i * 16 + lid;
        af[i] = *(const bf16x8*)(&As[buf][row * 64 + ((kk * 4 + quad) ^ (row & 7)) * 8]);
      }
#pragma unroll
      for (int j = 0; j < 4; j++) {
        int row = wn + j * 16 + lid;
        bfr[j] = *(const bf16x8*)(&Bs[buf][row * 64 + ((kk * 4 + quad) ^ (row & 7)) * 8]);
      }
#pragma unroll
      for (int i = 0; i < 4; i++)
#pragma unroll
        for (int j = 0; j < 4; j++)
          acc[i][j] = __builtin_amdgcn_mfma_f32_16x16x32_bf16(af[i], bfr[j], acc[i][j], 0, 0, 0);
    }
  };

  issueA(0, 0);
  loadB(0);
  writeB(0);
  __syncthreads();

  int cur = 0;
#pragma unroll 1
  for (int k0 = 64; k0 < K; k0 += 64) {
    issueA(cur ^ 1, k0);
    loadB(k0);
    __builtin_amdgcn_sched_barrier(0);
    compute(cur);
    __builtin_amdgcn_sched_barrier(0);
    writeB(cur ^ 1);
    __syncthreads();
    cur ^= 1;
  }
  compute(cur);

#pragma unroll
  for (int i = 0; i < 4; i++)
#pragma unroll
    for (int j = 0; j < 4; j++)
#pragma unroll
      for (int r = 0; r < 4; r++) {
        int m = bm * 128 + wm + i * 16 + quad * 4 + r;
        int n = bn * 256 + wn + j * 16 + lid;
        C[(size_t)m * N + n] = (CT)acc[i][j][r];
      }
}

// ---------------------------------------------------------------------------
extern "C" void kernel_launch(void* const* d_in, const int* in_sizes, int n_in,
                              void* d_out, int out_size, void* d_ws, size_t ws_size,
                              hipStream_t stream) {
  const float* hs  = (const float*)d_in[0];
  const float* kca = (const float*)d_in[1];
  const float* vca = (const float*)d_in[2];
  const float* Wq  = (const float*)d_in[3];
  const float* Wo  = (const float*)d_in[4];
  const int*   bt  = (const int*)d_in[5];
  float* out = (float*)d_out;

  // Scratch plan:
  //   ws[0..16MiB)      : Qlin bf16 -> rope in place -> ctx in place
  //   ws[16..48MiB)     : Wq_bf bf16 [4096][4096]   (big-ws path)
  //   ws[48..80MiB)     : Wo_bf bf16 [4096][4096]   (big-ws path)
  //   d_out[0..8MiB)    : Kg bf16 [8][4096][128]    (dead before oproj)
  //   d_out[8..16MiB)   : Vt bf16 [8][128][4096]    (dead before oproj)
  //   d_out[16..32MiB)  : hs_bf bf16 [2048][4096]   (dead after qproj)
  bf16* Qlin  = (bf16*)d_ws;
  bf16* Kg    = (bf16*)d_out;
  bf16* Vt    = (bf16*)((char*)d_out + (8u << 20));
  bf16* hs_bf = (bf16*)((char*)d_out + (16u << 20));

  prep_k<<<4096, 256, 0, stream>>>(kca, bt, Kg);
  prep_v<<<1024, 256, 0, stream>>>(vca, bt, Vt);
  prep_hs<<<4096, 256, 0, stream>>>(hs, hs_bf);

  if (ws_size >= (80u << 20)) {
    bf16* Wq_bf = (bf16*)((char*)d_ws + (16u << 20));
    bf16* Wo_bf = (bf16*)((char*)d_ws + (48u << 20));
    prep_w2<<<16384, 256, 0, stream>>>(Wq, Wo, Wq_bf, Wo_bf);
    gemm_w8<bf16><<<512, 512, 0, stream>>>(hs_bf, Wq_bf, Qlin, SEQ, HID, HID);
    rope_q<<<SEQ, 256, 0, stream>>>(Qlin);
    attn<<<512, 256, 0, stream>>>(Qlin, Kg, Vt);
    gemm_w8<float><<<512, 512, 0, stream>>>(Qlin, Wo_bf, out, SEQ, HID, HID);
  } else {
    gemm_bt2<bf16><<<256, 512, 0, stream>>>(hs_bf, Wq, Qlin, SEQ, HID, HID);
    rope_q<<<SEQ, 256, 0, stream>>>(Qlin);
    attn<<<512, 256, 0, stream>>>(Qlin, Kg, Vt);
    gemm_bt2<float><<<256, 512, 0, stream>>>(Qlin, Wo, out, SEQ, HID, HID);
  }
}